// Round 2
// baseline (131.651 us; speedup 1.0000x reference)
//
#include <hip/hip_runtime.h>

#define N_P   512
#define N_DIMC 3
#define N_K   32
#define N_T   10
#define BATCHC 8
#define EPSC  1e-6f
#define LOG2E 1.4426950408889634f
#define LN2   0.6931471805599453f

typedef float f2 __attribute__((ext_vector_type(2)));

// ws layout (floats): [0..31] w_eff[k], [32..63] ig2[k], [64] const_term

__global__ void prep_kernel(const float* __restrict__ t,
                            const float* __restrict__ mus_time,
                            const float* __restrict__ nlg_time,
                            const float* __restrict__ weights,
                            const float* __restrict__ bias,
                            const float* __restrict__ importance,
                            const float* __restrict__ nlg,
                            float* __restrict__ ws,
                            float* __restrict__ out) {
    __shared__ float trbf[N_T];
    __shared__ float w_eff_s[N_K];
    int k = threadIdx.x;
    // zero the divergence outputs (poisoned 0xAA before every timed launch)
    if (k < BATCHC) out[BATCHC * N_P * N_DIMC + k] = 0.f;
    if (k == 0) {
        float t0 = t[0];
        float r[N_T];
        float s = 0.f;
        for (int tt = 0; tt < N_T; ++tt) {
            float g = __expf(nlg_time[tt]);
            float diff = t0 - mus_time[tt];
            r[tt] = __expf(-diff * diff * g * g);
            s += r[tt];
        }
        float inv = 1.f / (EPSC + s);
        for (int tt = 0; tt < N_T; ++tt) trbf[tt] = r[tt] * inv;
    }
    __syncthreads();
    if (k < N_K) {
        float w = 0.f;
        for (int tt = 0; tt < N_T; ++tt) w = fmaf(weights[k * N_T + tt], trbf[tt], w);
        ws[k] = w;
        w_eff_s[k] = w;
        float g = __expf(nlg[k]);
        ws[N_K + k] = g * g;
    }
    __syncthreads();
    if (k == 0) {
        float c = 0.f;
        for (int tt = 0; tt < N_T; ++tt) c = fmaf(bias[tt], trbf[tt], c);
        for (int kk = 0; kk < N_K; ++kk) {
            float im = importance[kk];
            c = fmaf(im * im, w_eff_s[kk], c);
        }
        ws[2 * N_K] = c;
    }
}

// block = 256 threads = 4 waves; wave w handles i = itile*4 + w, lanes sweep j.
__global__ __launch_bounds__(256) void
pair_kernel(const float* __restrict__ x,
            const float* __restrict__ mus,
            const float* __restrict__ ws,
            float* __restrict__ out) {
    const int b     = blockIdx.x >> 7;        // 128 itiles per batch
    const int itile = blockIdx.x & 127;

    __shared__ float sx[N_P], sy[N_P], sz[N_P];

    const float* xb = x + b * (N_P * N_DIMC);
    for (int idx = threadIdx.x; idx < N_P * N_DIMC; idx += 256) {
        float v = xb[idx];
        int p = idx / 3;
        int c = idx - 3 * p;
        if (c == 0) sx[p] = v;
        else if (c == 1) sy[p] = v;
        else sz[p] = v;
    }

    // per-k constants packed as (k, k+16); uniform loads -> SGPRs
    f2 muk[N_K / 2], ig2l[N_K / 2], wk[N_K / 2];
#pragma unroll
    for (int k = 0; k < N_K / 2; ++k) {
        muk[k]  = (f2){mus[k], mus[k + 16]};
        ig2l[k] = (f2){ws[N_K + k] * LOG2E, ws[N_K + k + 16] * LOG2E};
        wk[k]   = (f2){ws[k], ws[k + 16]};
    }
    const float cterm = ws[2 * N_K];

    __syncthreads();

    const int wave = threadIdx.x >> 6;
    const int lane = threadIdx.x & 63;
    const int i = itile * 4 + wave;

    const float xi_x = sx[i], xi_y = sy[i], xi_z = sz[i];

    float fx = 0.f, fy = 0.f, fz = 0.f, dva = 0.f, dvb = 0.f;

#pragma unroll 2
    for (int jj = 0; jj < N_P / 64; ++jj) {
        int j = jj * 64 + lane;
        float dx = xi_x - sx[j];
        float dy = xi_y - sy[j];
        float dz = xi_z - sz[j];
        float dsq = fmaf(dx, dx, fmaf(dy, dy, dz * dz)) + EPSC;
        float d = __builtin_amdgcn_sqrtf(dsq);

        f2 dd = (f2){d, d};
        f2 rs = (f2){0.f, 0.f}, wes = rs, dss = rs, wdss = rs;
#pragma unroll
        for (int k = 0; k < N_K / 2; ++k) {
            f2 diff = dd - muk[k];
            f2 tt = diff * ig2l[k];      // diff * ig2 * log2e
            f2 arg = -(diff * tt);       // -diff^2 * ig2 * log2e
            f2 e;
            e.x = exp2f(arg.x);
            e.y = exp2f(arg.y);
            f2 te = tt * e;
            rs   += e;
            wes  += wk[k] * e;
            dss  += te;
            wdss += wk[k] * te;
        }
        float rsum = rs.x + rs.y;
        float we   = wes.x + wes.y;
        float ds   = dss.x + dss.y;     // scaled by log2e
        float wds  = wdss.x + wdss.y;   // scaled by log2e

        float inv  = __builtin_amdgcn_rcpf(EPSC + rsum);
        float fmag = fmaf(we, inv, cterm);
        // dfm = -2*inv*(wds_true - we*inv*ds_true); *ln2 un-scales log2e
        float dfm  = (-2.f * LN2) * inv * fmaf(-we * inv, ds, wds);

        bool self = (j == i);
        fmag = self ? 0.f : fmag;
        dfm  = self ? 0.f : dfm;

        fx  = fmaf(dx, fmag, fx);
        fy  = fmaf(dy, fmag, fy);
        fz  = fmaf(dz, fmag, fz);
        dva = fmaf(d, dfm, dva);
        dvb += fmag;
    }
    float dv = fmaf(3.f, dvb, dva);

    // wave-level reduction only (each wave owns its i)
#pragma unroll
    for (int off = 32; off >= 1; off >>= 1) {
        fx += __shfl_down(fx, off, 64);
        fy += __shfl_down(fy, off, 64);
        fz += __shfl_down(fz, off, 64);
        dv += __shfl_down(dv, off, 64);
    }
    if (lane == 0) {
        float* outf = out + (b * N_P + i) * 3;
        outf[0] = fx;
        outf[1] = fy;
        outf[2] = fz;
        atomicAdd(out + BATCHC * N_P * N_DIMC + b, -dv);
    }
}

extern "C" void kernel_launch(void* const* d_in, const int* in_sizes, int n_in,
                              void* d_out, int out_size, void* d_ws, size_t ws_size,
                              hipStream_t stream) {
    const float* t          = (const float*)d_in[0];
    const float* x          = (const float*)d_in[1];
    const float* mus        = (const float*)d_in[2];
    const float* nlg        = (const float*)d_in[3];
    const float* mus_time   = (const float*)d_in[4];
    const float* nlg_time   = (const float*)d_in[5];
    const float* weights    = (const float*)d_in[6];
    const float* bias       = (const float*)d_in[7];
    const float* importance = (const float*)d_in[8];
    float* out = (float*)d_out;
    float* ws  = (float*)d_ws;

    prep_kernel<<<1, 64, 0, stream>>>(t, mus_time, nlg_time, weights, bias,
                                      importance, nlg, ws, out);
    pair_kernel<<<BATCHC * (N_P / 4), 256, 0, stream>>>(x, mus, ws, out);
}

// Round 3
// 89.523 us; speedup vs baseline: 1.4706x; 1.4706x over previous
//
#include <hip/hip_runtime.h>

#define N_P   512
#define N_DIMC 3
#define N_K   32
#define N_T   10
#define BATCHC 8
#define EPSC  1e-6f
#define LOG2E 1.4426950408889634f
#define LN2   0.6931471805599453f

typedef float f2 __attribute__((ext_vector_type(2)));

// ws layout (floats): [0..31] w_eff[k], [32..63] ig2[k], [64] const_term

__global__ void prep_kernel(const float* __restrict__ t,
                            const float* __restrict__ mus_time,
                            const float* __restrict__ nlg_time,
                            const float* __restrict__ weights,
                            const float* __restrict__ bias,
                            const float* __restrict__ importance,
                            const float* __restrict__ nlg,
                            float* __restrict__ ws,
                            float* __restrict__ out) {
    __shared__ float trbf[N_T];
    __shared__ float w_eff_s[N_K];
    int k = threadIdx.x;
    // zero the divergence outputs (poisoned 0xAA before every timed launch)
    if (k < BATCHC) out[BATCHC * N_P * N_DIMC + k] = 0.f;
    if (k == 0) {
        float t0 = t[0];
        float r[N_T];
        float s = 0.f;
        for (int tt = 0; tt < N_T; ++tt) {
            float g = __expf(nlg_time[tt]);
            float diff = t0 - mus_time[tt];
            r[tt] = __expf(-diff * diff * g * g);
            s += r[tt];
        }
        float inv = 1.f / (EPSC + s);
        for (int tt = 0; tt < N_T; ++tt) trbf[tt] = r[tt] * inv;
    }
    __syncthreads();
    if (k < N_K) {
        float w = 0.f;
        for (int tt = 0; tt < N_T; ++tt) w = fmaf(weights[k * N_T + tt], trbf[tt], w);
        ws[k] = w;
        w_eff_s[k] = w;
        float g = __expf(nlg[k]);
        ws[N_K + k] = g * g;
    }
    __syncthreads();
    if (k == 0) {
        float c = 0.f;
        for (int tt = 0; tt < N_T; ++tt) c = fmaf(bias[tt], trbf[tt], c);
        for (int kk = 0; kk < N_K; ++kk) {
            float im = importance[kk];
            c = fmaf(im * im, w_eff_s[kk], c);
        }
        ws[2 * N_K] = c;
    }
}

// block = 512 threads = 8 waves; wave w: i = itile*4 + (w&3), j-half = w>>2.
// Grid = 1024 blocks -> 8192 waves = 8/SIMD (full occupancy at 36 VGPR).
__global__ __launch_bounds__(512) void
pair_kernel(const float* __restrict__ x,
            const float* __restrict__ mus,
            const float* __restrict__ ws,
            float* __restrict__ out) {
    const int b     = blockIdx.x >> 7;        // 128 itiles per batch
    const int itile = blockIdx.x & 127;

    __shared__ float sx[N_P], sy[N_P], sz[N_P];
    __shared__ float red[8][4];

    const float* xb = x + b * (N_P * N_DIMC);
#pragma unroll
    for (int idx = threadIdx.x; idx < N_P * N_DIMC; idx += 512) {
        float v = xb[idx];
        int p = idx / 3;
        int c = idx - 3 * p;
        if (c == 0) sx[p] = v;
        else if (c == 1) sy[p] = v;
        else sz[p] = v;
    }

    // per-k constants packed as (k, k+16); uniform loads -> SGPRs
    f2 muk[N_K / 2], ig2l[N_K / 2], wk[N_K / 2];
#pragma unroll
    for (int k = 0; k < N_K / 2; ++k) {
        muk[k]  = (f2){mus[k], mus[k + 16]};
        ig2l[k] = (f2){ws[N_K + k] * LOG2E, ws[N_K + k + 16] * LOG2E};
        wk[k]   = (f2){ws[k], ws[k + 16]};
    }
    const float cterm = ws[2 * N_K];

    __syncthreads();

    const int wid   = threadIdx.x >> 6;
    const int lane  = threadIdx.x & 63;
    const int i     = itile * 4 + (wid & 3);
    const int jbase = (wid >> 2) * (N_P / 2);

    const float xi_x = sx[i], xi_y = sy[i], xi_z = sz[i];

    float fx = 0.f, fy = 0.f, fz = 0.f, dva = 0.f, dvb = 0.f;

#pragma unroll 2
    for (int jj = 0; jj < N_P / 2 / 64; ++jj) {
        int j = jbase + jj * 64 + lane;
        float dx = xi_x - sx[j];
        float dy = xi_y - sy[j];
        float dz = xi_z - sz[j];
        float dsq = fmaf(dx, dx, fmaf(dy, dy, dz * dz)) + EPSC;
        float d = __builtin_amdgcn_sqrtf(dsq);

        f2 dd = (f2){d, d};
        f2 rs = (f2){0.f, 0.f}, wes = rs, dss = rs, wdss = rs;
#pragma unroll
        for (int k = 0; k < N_K / 2; ++k) {
            f2 diff = dd - muk[k];
            f2 tt = diff * ig2l[k];      // diff * ig2 * log2e
            f2 arg = -(diff * tt);       // -diff^2 * ig2 * log2e
            f2 e;
            e.x = __builtin_amdgcn_exp2f(arg.x);   // raw v_exp_f32, no OCML fixup
            e.y = __builtin_amdgcn_exp2f(arg.y);
            f2 te = tt * e;
            rs   += e;
            wes  += wk[k] * e;
            dss  += te;
            wdss += wk[k] * te;
        }
        float rsum = rs.x + rs.y;
        float we   = wes.x + wes.y;
        float ds   = dss.x + dss.y;     // scaled by log2e
        float wds  = wdss.x + wdss.y;   // scaled by log2e

        float inv  = __builtin_amdgcn_rcpf(EPSC + rsum);
        float fmag = fmaf(we, inv, cterm);
        // dfm = -2*inv*(wds_true - we*inv*ds_true); *ln2 un-scales log2e
        float dfm  = (-2.f * LN2) * inv * fmaf(-we * inv, ds, wds);

        bool self = (j == i);
        fmag = self ? 0.f : fmag;
        dfm  = self ? 0.f : dfm;

        fx  = fmaf(dx, fmag, fx);
        fy  = fmaf(dy, fmag, fy);
        fz  = fmaf(dz, fmag, fz);
        dva = fmaf(d, dfm, dva);
        dvb += fmag;
    }
    float dv = fmaf(3.f, dvb, dva);

    // wave-level reduction (each wave owns one (i, j-half))
#pragma unroll
    for (int off = 32; off >= 1; off >>= 1) {
        fx += __shfl_down(fx, off, 64);
        fy += __shfl_down(fy, off, 64);
        fz += __shfl_down(fz, off, 64);
        dv += __shfl_down(dv, off, 64);
    }
    if (lane == 0) {
        red[wid][0] = fx; red[wid][1] = fy; red[wid][2] = fz; red[wid][3] = dv;
    }
    __syncthreads();
    // combine the two j-halves (waves w and w+4) and write out
    if (threadIdx.x < 4) {
        int t = threadIdx.x;
        int ii = itile * 4 + t;
        float tfx = red[t][0] + red[t + 4][0];
        float tfy = red[t][1] + red[t + 4][1];
        float tfz = red[t][2] + red[t + 4][2];
        float tdv = red[t][3] + red[t + 4][3];
        float* outf = out + (b * N_P + ii) * 3;
        outf[0] = tfx;
        outf[1] = tfy;
        outf[2] = tfz;
        atomicAdd(out + BATCHC * N_P * N_DIMC + b, -tdv);
    }
}

extern "C" void kernel_launch(void* const* d_in, const int* in_sizes, int n_in,
                              void* d_out, int out_size, void* d_ws, size_t ws_size,
                              hipStream_t stream) {
    const float* t          = (const float*)d_in[0];
    const float* x          = (const float*)d_in[1];
    const float* mus        = (const float*)d_in[2];
    const float* nlg        = (const float*)d_in[3];
    const float* mus_time   = (const float*)d_in[4];
    const float* nlg_time   = (const float*)d_in[5];
    const float* weights    = (const float*)d_in[6];
    const float* bias       = (const float*)d_in[7];
    const float* importance = (const float*)d_in[8];
    float* out = (float*)d_out;
    float* ws  = (float*)d_ws;

    prep_kernel<<<1, 64, 0, stream>>>(t, mus_time, nlg_time, weights, bias,
                                      importance, nlg, ws, out);
    pair_kernel<<<BATCHC * (N_P / 4), 512, 0, stream>>>(x, mus, ws, out);
}